// Round 1
// baseline (8786.720 us; speedup 1.0000x reference)
//
#include <hip/hip_runtime.h>

// ---------------------------------------------------------------------------
// Seq2seq: 3-layer LSTM encoder + 3-layer LSTM decoder + dense vocab head
// B=32 T=128 V=32000 E=H=1024 L=3
// Internal layout: sequences stored [T][B][*] so each timestep's 32 rows are
// contiguous. Final dense epilogue permutes rows back to [B][T][V].
// ---------------------------------------------------------------------------

typedef __bf16 bf8 __attribute__((ext_vector_type(8)));
typedef float  f4  __attribute__((ext_vector_type(4)));

#define BATCH 32
#define TLEN  128
#define EMB   1024
#define HID   1024
#define G4    4096   // 4*HID
#define VOC   32000

__device__ __forceinline__ ushort f2bf(float f) {
  unsigned u = __builtin_bit_cast(unsigned, f);
  u += 0x7fffu + ((u >> 16) & 1u);          // round-to-nearest-even
  return (ushort)(u >> 16);
}
__device__ __forceinline__ float sigmoidf_(float x) { return 1.f / (1.f + expf(-x)); }

// --- embedding gather: out[t*32+b][e] = bf16(emb[ids[b][t]][e]) -------------
__global__ __launch_bounds__(256) void embed_kernel(const int* __restrict__ ids,
    const float* __restrict__ emb, ushort* __restrict__ out) {
  int r = blockIdx.x;            // r = t*32 + b
  int b = r & 31, t = r >> 5;
  int id = ids[b * TLEN + t];
  const float4* src = (const float4*)(emb + (size_t)id * EMB);
  float4 v = src[threadIdx.x];
  ushort4 o;
  o.x = f2bf(v.x); o.y = f2bf(v.y); o.z = f2bf(v.z); o.w = f2bf(v.w);
  *(ushort4*)(out + (size_t)r * EMB + threadIdx.x * 4) = o;
}

// --- f32 [R][C] -> bf16 [C][R] tiled transpose ------------------------------
__global__ __launch_bounds__(256) void transpose_cvt(const float* __restrict__ W,
    ushort* __restrict__ Wt, int R, int C) {
  __shared__ float tile[32][33];
  int tx = threadIdx.x & 31, ty = threadIdx.x >> 5;   // ty 0..7
  int c0 = blockIdx.x * 32, r0 = blockIdx.y * 32;
  #pragma unroll
  for (int i = 0; i < 32; i += 8)
    tile[ty + i][tx] = W[(size_t)(r0 + ty + i) * C + c0 + tx];
  __syncthreads();
  #pragma unroll
  for (int i = 0; i < 32; i += 8)
    Wt[(size_t)(c0 + ty + i) * R + r0 + tx] = f2bf(tile[tx][ty + i]);
}

// --- bf16 MFMA GEMM: C[M][N] = A[M][K] @ Bt[N][K]^T + bias ------------------
// 128x128 tile, BK=32, 4 waves (2x2), each wave 4x4 16x16 frags (m97-style).
// permute: output row r=t*32+b remapped to b*128+t (for final logits).
__global__ __launch_bounds__(256) void gemm_bt(const ushort* __restrict__ A,
    const ushort* __restrict__ Bt, const float* __restrict__ bias,
    float* __restrict__ C, int M, int N, int K, int permute) {
  __shared__ __align__(16) ushort lA[128 * 32];
  __shared__ __align__(16) ushort lB[128 * 32];
  int tid = threadIdx.x;
  int lane = tid & 63, wave = tid >> 6;
  int m0 = blockIdx.y * 128, n0 = blockIdx.x * 128;
  int wr = wave >> 1, wc = wave & 1;
  f4 zero = {0.f, 0.f, 0.f, 0.f};
  f4 acc[4][4];
  #pragma unroll
  for (int i = 0; i < 4; i++)
    #pragma unroll
    for (int j = 0; j < 4; j++) acc[i][j] = zero;

  for (int kt = 0; kt < K; kt += 32) {
    #pragma unroll
    for (int p = 0; p < 2; p++) {
      int q = p * 256 + tid;       // chunk id 0..511, 8 bf16 per chunk
      int row = q >> 2;            // 0..127
      int kof = (q & 3) * 8;
      *(bf8*)(lA + q * 8) = *(const bf8*)(A + (size_t)(m0 + row) * K + kt + kof);
      *(bf8*)(lB + q * 8) = *(const bf8*)(Bt + (size_t)(n0 + row) * K + kt + kof);
    }
    __syncthreads();
    bf8 aF[4], bF[4];
    #pragma unroll
    for (int i = 0; i < 4; i++)
      aF[i] = *(const bf8*)(lA + (wr * 64 + i * 16 + (lane & 15)) * 32 + (lane >> 4) * 8);
    #pragma unroll
    for (int j = 0; j < 4; j++)
      bF[j] = *(const bf8*)(lB + (wc * 64 + j * 16 + (lane & 15)) * 32 + (lane >> 4) * 8);
    #pragma unroll
    for (int i = 0; i < 4; i++)
      #pragma unroll
      for (int j = 0; j < 4; j++)
        acc[i][j] = __builtin_amdgcn_mfma_f32_16x16x32_bf16(aF[i], bF[j], acc[i][j], 0, 0, 0);
    __syncthreads();
  }
  #pragma unroll
  for (int i = 0; i < 4; i++) {
    #pragma unroll
    for (int j = 0; j < 4; j++) {
      int col = n0 + wc * 64 + j * 16 + (lane & 15);
      float bv = bias ? bias[col] : 0.f;
      #pragma unroll
      for (int v = 0; v < 4; v++) {
        int row = m0 + wr * 64 + i * 16 + (lane >> 4) * 4 + v;
        int orow = permute ? ((row & 31) * TLEN + (row >> 5)) : row;
        C[(size_t)orow * N + col] = acc[i][j][v] + bv;
      }
    }
  }
}

// --- one LSTM timestep: z = Zpre[t] + h@Wh, gates, c/h update ---------------
// grid (2,64): blockIdx.x = which 16 batch rows, blockIdx.y = 16 j-columns.
// 4 waves = 4 gates (i,f,g,o); each wave one 16x16 MFMA tile over K=1024.
// h and Wht read directly from global (L2-resident, stable WG->col mapping).
__global__ __launch_bounds__(256) void lstm_step(const float* __restrict__ Zt,
    const ushort* __restrict__ hprev, const ushort* __restrict__ Wht,
    float* __restrict__ c, ushort* __restrict__ yout) {
  int mhalf = blockIdx.x;
  int jg = blockIdx.y;
  int lane = threadIdx.x & 63, wave = threadIdx.x >> 6;
  int j0 = jg * 16;
  const ushort* Ap = hprev + (size_t)(mhalf * 16 + (lane & 15)) * HID + (lane >> 4) * 8;
  const ushort* Bp = Wht + (size_t)(wave * HID + j0 + (lane & 15)) * HID + (lane >> 4) * 8;
  f4 acc = {0.f, 0.f, 0.f, 0.f};
  #pragma unroll 8
  for (int kt = 0; kt < HID; kt += 32) {
    bf8 a = *(const bf8*)(Ap + kt);
    bf8 b = *(const bf8*)(Bp + kt);
    acc = __builtin_amdgcn_mfma_f32_16x16x32_bf16(a, b, acc, 0, 0, 0);
  }
  __shared__ float zbuf[4][16][16];
  #pragma unroll
  for (int v = 0; v < 4; v++)
    zbuf[wave][(lane >> 4) * 4 + v][lane & 15] = acc[v];
  __syncthreads();
  int rr = threadIdx.x >> 4, jj = threadIdx.x & 15;   // 16x16 threads
  int row = mhalf * 16 + rr;                          // batch row 0..31
  int j = j0 + jj;
  float zi = Zt[(size_t)row * G4 + j]           + zbuf[0][rr][jj];
  float zf = Zt[(size_t)row * G4 + HID + j]     + zbuf[1][rr][jj];
  float zg = Zt[(size_t)row * G4 + 2 * HID + j] + zbuf[2][rr][jj];
  float zo = Zt[(size_t)row * G4 + 3 * HID + j] + zbuf[3][rr][jj];
  float ig = sigmoidf_(zi), fg = sigmoidf_(zf), gg = tanhf(zg), og = sigmoidf_(zo);
  float cn = fg * c[row * HID + j] + ig * gg;
  c[row * HID + j] = cn;
  yout[row * HID + j] = f2bf(og * tanhf(cn));
}

// --- tiny state helpers -----------------------------------------------------
__global__ __launch_bounds__(256) void zero_state(ushort* h0, float* c) {
  int i = blockIdx.x * 256 + threadIdx.x;   // 128 blocks * 256 = 32768
  h0[i] = 0; c[i] = 0.f;
}
__global__ __launch_bounds__(256) void copy_h0(const ushort* __restrict__ src,
                                               ushort* __restrict__ h0) {
  int i = blockIdx.x * 256 + threadIdx.x;
  h0[i] = src[i];
}

// ---------------------------------------------------------------------------
extern "C" void kernel_launch(void* const* d_in, const int* in_sizes, int n_in,
                              void* d_out, int out_size, void* d_ws, size_t ws_size,
                              hipStream_t stream) {
  const int*   enc_ids = (const int*)d_in[0];
  const int*   dec_ids = (const int*)d_in[1];
  const float* emb     = (const float*)d_in[2];
  const float* Wx_enc  = (const float*)d_in[3];
  const float* Wh_enc  = (const float*)d_in[4];
  const float* b_enc   = (const float*)d_in[5];
  const float* Wx_dec  = (const float*)d_in[6];
  const float* Wh_dec  = (const float*)d_in[7];
  const float* b_dec   = (const float*)d_in[8];
  const float* dense_W = (const float*)d_in[9];
  const float* dense_b = (const float*)d_in[10];
  float* out = (float*)d_out;

  // workspace layout (~95 MiB): bufA, bufB (bf16 x/y ping-pong), Wxt, Wht
  // (per-layer bf16 [N][K]), dWt (dense W bf16 [V][H]), h0, c.
  char* ws = (char*)d_ws;
  const size_t SZ_BUF = (size_t)4096 * 1024 * 2;   // 8 MiB
  ushort* bufA = (ushort*)(ws);
  ushort* bufB = (ushort*)(ws + SZ_BUF);
  ushort* Wxt  = (ushort*)(ws + 2 * SZ_BUF);
  ushort* Wht  = (ushort*)(ws + 3 * SZ_BUF);
  ushort* dWt  = (ushort*)(ws + 4 * SZ_BUF);       // VOC*1024*2 = 65,536,000 B
  char*   p2   = ws + 4 * SZ_BUF + (size_t)VOC * 1024 * 2;
  ushort* h0   = (ushort*)p2;                       // 32*1024 bf16
  float*  cst  = (float*)(p2 + (size_t)32 * 1024 * 2); // 32*1024 f32
  float*  Zpre = out;   // 64 MB scratch inside d_out (dead before final GEMM)

  // dense head weight transpose (done once, needed only at the end)
  transpose_cvt<<<dim3(VOC / 32, 1024 / 32), 256, 0, stream>>>(dense_W, dWt, 1024, VOC);

  // ---------------- encoder ----------------
  embed_kernel<<<4096, 256, 0, stream>>>(enc_ids, emb, bufA);
  ushort* cur = bufA; ushort* oth = bufB;
  for (int l = 0; l < 3; l++) {
    transpose_cvt<<<dim3(G4 / 32, 32), 256, 0, stream>>>(Wx_enc + (size_t)l * 1024 * G4, Wxt, 1024, G4);
    transpose_cvt<<<dim3(G4 / 32, 32), 256, 0, stream>>>(Wh_enc + (size_t)l * 1024 * G4, Wht, 1024, G4);
    gemm_bt<<<dim3(G4 / 128, 4096 / 128), 256, 0, stream>>>(cur, Wxt, b_enc + (size_t)l * G4,
                                                            Zpre, 4096, G4, 1024, 0);
    zero_state<<<128, 256, 0, stream>>>(h0, cst);
    for (int t = 0; t < TLEN; t++) {
      const ushort* hp = (t == 0) ? h0 : oth + (size_t)(t - 1) * 32 * HID;
      lstm_step<<<dim3(2, 64), 256, 0, stream>>>(Zpre + (size_t)t * 32 * G4, hp, Wht, cst,
                                                 oth + (size_t)t * 32 * HID);
    }
    ushort* tmp = cur; cur = oth; oth = tmp;
  }
  // cur = encoder final y; its rows 127*32.. hold h_T of enc layer 2
  ushort* encY = cur;

  // ---------------- decoder ----------------
  embed_kernel<<<4096, 256, 0, stream>>>(dec_ids, emb, oth);
  { ushort* tmp = cur; cur = oth; oth = tmp; }   // cur = dec input, oth = encY buffer
  for (int l = 0; l < 3; l++) {
    transpose_cvt<<<dim3(G4 / 32, 32), 256, 0, stream>>>(Wx_dec + (size_t)l * 1024 * G4, Wxt, 1024, G4);
    transpose_cvt<<<dim3(G4 / 32, 32), 256, 0, stream>>>(Wh_dec + (size_t)l * 1024 * G4, Wht, 1024, G4);
    gemm_bt<<<dim3(G4 / 128, 4096 / 128), 256, 0, stream>>>(cur, Wxt, b_dec + (size_t)l * G4,
                                                            Zpre, 4096, G4, 1024, 0);
    // h0 = previous stage's final h; c carries over in cst (faithful chaining)
    const ushort* h0src = (l == 0 ? encY : cur) + (size_t)127 * 32 * HID;
    copy_h0<<<128, 256, 0, stream>>>(h0src, h0);
    for (int t = 0; t < TLEN; t++) {
      const ushort* hp = (t == 0) ? h0 : oth + (size_t)(t - 1) * 32 * HID;
      lstm_step<<<dim3(2, 64), 256, 0, stream>>>(Zpre + (size_t)t * 32 * G4, hp, Wht, cst,
                                                 oth + (size_t)t * 32 * HID);
    }
    ushort* tmp = cur; cur = oth; oth = tmp;
  }
  // cur = decoder final y [T*B][H] (bf16)

  // ---------------- dense head: logits[b][t][v] ----------------
  gemm_bt<<<dim3(VOC / 128, 4096 / 128), 256, 0, stream>>>(cur, dWt, dense_b, out,
                                                           4096, VOC, 1024, 1);
}